// Round 1
// baseline (102.976 us; speedup 1.0000x reference)
//
#include <hip/hip_runtime.h>

// NeighborList: N atoms, minimum-image convention, cutoff 5.0.
// Output layout (all float32): pairs[2*P], deltas[P*3], distances[P], n_pairs[1]
// Ordering must match jnp.nonzero(mask.ravel()) -> ascending flat index i*N+j.

#define CUT2 25.0f

__device__ __forceinline__ void load_box_inv(const float* __restrict__ box,
                                             float B[3][3], float Binv[3][3]) {
    #pragma unroll
    for (int r = 0; r < 3; ++r)
        #pragma unroll
        for (int c = 0; c < 3; ++c)
            B[r][c] = box[r * 3 + c];

    float a00 = B[0][0], a01 = B[0][1], a02 = B[0][2];
    float a10 = B[1][0], a11 = B[1][1], a12 = B[1][2];
    float a20 = B[2][0], a21 = B[2][1], a22 = B[2][2];

    // adjugate entries (cofactor transpose)
    float adj00 =  (a11 * a22 - a12 * a21);
    float adj01 = -(a01 * a22 - a02 * a21);
    float adj02 =  (a01 * a12 - a02 * a11);
    float adj10 = -(a10 * a22 - a12 * a20);
    float adj11 =  (a00 * a22 - a02 * a20);
    float adj12 = -(a00 * a12 - a02 * a10);
    float adj20 =  (a10 * a21 - a11 * a20);
    float adj21 = -(a00 * a21 - a01 * a20);
    float adj22 =  (a00 * a11 - a01 * a10);

    float det = a00 * adj00 + a01 * adj10 + a02 * adj20;

    // per-entry division: for diagonal box this rounds identically to
    // LAPACK's 1/pivot (single rounding of the exact quotient).
    Binv[0][0] = __fdiv_rn(adj00, det); Binv[0][1] = __fdiv_rn(adj01, det); Binv[0][2] = __fdiv_rn(adj02, det);
    Binv[1][0] = __fdiv_rn(adj10, det); Binv[1][1] = __fdiv_rn(adj11, det); Binv[1][2] = __fdiv_rn(adj12, det);
    Binv[2][0] = __fdiv_rn(adj20, det); Binv[2][1] = __fdiv_rn(adj21, det); Binv[2][2] = __fdiv_rn(adj22, det);
}

// Replicates numpy rounding exactly (no FMA contraction):
// delta = pos_i - pos_j; frac = delta @ Binv; delta -= rint(frac) @ B; d2 = sum(delta^2)
__device__ __forceinline__ void min_image(float xi, float yi, float zi,
                                          float xj, float yj, float zj,
                                          const float B[3][3], const float Binv[3][3],
                                          float& dx, float& dy, float& dz, float& d2) {
    dx = __fsub_rn(xi, xj);
    dy = __fsub_rn(yi, yj);
    dz = __fsub_rn(zi, zj);

    float f0 = __fadd_rn(__fadd_rn(__fmul_rn(dx, Binv[0][0]), __fmul_rn(dy, Binv[1][0])), __fmul_rn(dz, Binv[2][0]));
    float f1 = __fadd_rn(__fadd_rn(__fmul_rn(dx, Binv[0][1]), __fmul_rn(dy, Binv[1][1])), __fmul_rn(dz, Binv[2][1]));
    float f2 = __fadd_rn(__fadd_rn(__fmul_rn(dx, Binv[0][2]), __fmul_rn(dy, Binv[1][2])), __fmul_rn(dz, Binv[2][2]));

    float r0 = rintf(f0), r1 = rintf(f1), r2 = rintf(f2);

    float c0 = __fadd_rn(__fadd_rn(__fmul_rn(r0, B[0][0]), __fmul_rn(r1, B[1][0])), __fmul_rn(r2, B[2][0]));
    float c1 = __fadd_rn(__fadd_rn(__fmul_rn(r0, B[0][1]), __fmul_rn(r1, B[1][1])), __fmul_rn(r2, B[2][1]));
    float c2 = __fadd_rn(__fadd_rn(__fmul_rn(r0, B[0][2]), __fmul_rn(r1, B[1][2])), __fmul_rn(r2, B[2][2]));

    dx = __fsub_rn(dx, c0);
    dy = __fsub_rn(dy, c1);
    dz = __fsub_rn(dz, c2);

    d2 = __fadd_rn(__fadd_rn(__fmul_rn(dx, dx), __fmul_rn(dy, dy)), __fmul_rn(dz, dz));
}

// Fill padding: pairs region = -1.0f, everything else = 0.0f.
__global__ void pad_out_kernel(float* __restrict__ out, int P) {
    int total = 6 * P + 1;
    for (int idx = blockIdx.x * blockDim.x + threadIdx.x; idx < total;
         idx += gridDim.x * blockDim.x) {
        out[idx] = (idx < 2 * P) ? -1.0f : 0.0f;
    }
}

// One wave per row i: count j>i hits.
__global__ void count_rows_kernel(const float* __restrict__ pos, const float* __restrict__ box,
                                  int* __restrict__ counts, int N) {
    int gwave = (blockIdx.x * blockDim.x + threadIdx.x) >> 6;
    int lane = threadIdx.x & 63;
    if (gwave >= N) return;
    int i = gwave;

    float B[3][3], Binv[3][3];
    load_box_inv(box, B, Binv);

    float xi = pos[3 * i + 0], yi = pos[3 * i + 1], zi = pos[3 * i + 2];

    int cnt = 0;
    int jb0 = (i >> 6) << 6;  // chunks fully below i contribute nothing
    for (int jb = jb0; jb < N; jb += 64) {
        int j = jb + lane;
        bool hit = false;
        if (j > i && j < N) {
            float dx, dy, dz, d2;
            min_image(xi, yi, zi, pos[3 * j + 0], pos[3 * j + 1], pos[3 * j + 2],
                      B, Binv, dx, dy, dz, d2);
            hit = (d2 < CUT2);
        }
        unsigned long long m = __ballot(hit);
        cnt += __popcll(m);
    }
    if (lane == 0) counts[i] = cnt;
}

// Single block: exclusive scan of counts[N] -> offsets[N]; write n_pairs.
__global__ void scan_counts_kernel(const int* __restrict__ counts, int* __restrict__ offsets,
                                   float* __restrict__ out_npairs, int N) {
    __shared__ int s[1024];
    int tid = threadIdx.x;
    int nper = (N + 1023) / 1024;  // elements per thread (4 for N=4096)

    int v[8];  // supports N up to 8192
    int sum = 0;
    for (int r = 0; r < nper; ++r) {
        int k = tid * nper + r;
        v[r] = (k < N) ? counts[k] : 0;
        sum += v[r];
    }
    s[tid] = sum;
    __syncthreads();

    // Hillis-Steele inclusive scan over 1024 thread sums
    for (int off = 1; off < 1024; off <<= 1) {
        int t = (tid >= off) ? s[tid - off] : 0;
        __syncthreads();
        s[tid] += t;
        __syncthreads();
    }

    int run = (tid == 0) ? 0 : s[tid - 1];
    for (int r = 0; r < nper; ++r) {
        int k = tid * nper + r;
        if (k < N) offsets[k] = run;
        run += v[r];
    }
    if (tid == 1023) *out_npairs = (float)s[1023];
}

// One wave per row i: ordered compaction of hits into out at offsets[i].
__global__ void fill_rows_kernel(const float* __restrict__ pos, const float* __restrict__ box,
                                 const int* __restrict__ offsets,
                                 float* __restrict__ out, int N, int P) {
    int gwave = (blockIdx.x * blockDim.x + threadIdx.x) >> 6;
    int lane = threadIdx.x & 63;
    if (gwave >= N) return;
    int i = gwave;

    float B[3][3], Binv[3][3];
    load_box_inv(box, B, Binv);

    float xi = pos[3 * i + 0], yi = pos[3 * i + 1], zi = pos[3 * i + 2];

    int base = offsets[i];
    int jb0 = (i >> 6) << 6;
    for (int jb = jb0; jb < N; jb += 64) {
        int j = jb + lane;
        bool hit = false;
        float dx = 0.f, dy = 0.f, dz = 0.f, d2 = 0.f;
        if (j > i && j < N) {
            min_image(xi, yi, zi, pos[3 * j + 0], pos[3 * j + 1], pos[3 * j + 2],
                      B, Binv, dx, dy, dz, d2);
            hit = (d2 < CUT2);
        }
        unsigned long long m = __ballot(hit);
        int my_pos = __popcll(m & ((1ull << lane) - 1ull));
        int slot = base + my_pos;
        if (hit && slot < P) {
            out[slot] = (float)i;                       // pair_i
            out[P + slot] = (float)j;                   // pair_j
            size_t db = 2 * (size_t)P + 3 * (size_t)slot;
            out[db + 0] = dx;
            out[db + 1] = dy;
            out[db + 2] = dz;
            out[5 * (size_t)P + slot] = sqrtf(d2);      // distance
        }
        base += __popcll(m);
    }
}

extern "C" void kernel_launch(void* const* d_in, const int* in_sizes, int n_in,
                              void* d_out, int out_size, void* d_ws, size_t ws_size,
                              hipStream_t stream) {
    const float* pos = (const float*)d_in[0];
    const float* box = (const float*)d_in[1];
    float* out = (float*)d_out;

    int N = in_sizes[0] / 3;          // 4096
    int P = (out_size - 1) / 6;       // 131072

    int* counts = (int*)d_ws;
    int* offsets = counts + N;

    int total_out = 6 * P + 1;
    int pad_blocks = (total_out + 255) / 256;
    pad_out_kernel<<<pad_blocks, 256, 0, stream>>>(out, P);

    int row_threads = N * 64;
    int row_blocks = (row_threads + 255) / 256;
    count_rows_kernel<<<row_blocks, 256, 0, stream>>>(pos, box, counts, N);

    scan_counts_kernel<<<1, 1024, 0, stream>>>(counts, offsets, out + 6 * (size_t)P, N);

    fill_rows_kernel<<<row_blocks, 256, 0, stream>>>(pos, box, offsets, out, N, P);
}

// Round 2
// 101.188 us; speedup vs baseline: 1.0177x; 1.0177x over previous
//
#include <hip/hip_runtime.h>

// NeighborList: N atoms, minimum-image convention, cutoff 5.0.
// Output layout (all float32): pairs[2*P], deltas[P*3], distances[P], n_pairs[1]
// Ordering must match jnp.nonzero(mask.ravel()) -> ascending flat index i*N+j.

#define CUT2 25.0f

__device__ __forceinline__ void load_box_inv(const float* __restrict__ box,
                                             float B[3][3], float Binv[3][3]) {
    #pragma unroll
    for (int r = 0; r < 3; ++r)
        #pragma unroll
        for (int c = 0; c < 3; ++c)
            B[r][c] = box[r * 3 + c];

    float a00 = B[0][0], a01 = B[0][1], a02 = B[0][2];
    float a10 = B[1][0], a11 = B[1][1], a12 = B[1][2];
    float a20 = B[2][0], a21 = B[2][1], a22 = B[2][2];

    float adj00 =  (a11 * a22 - a12 * a21);
    float adj01 = -(a01 * a22 - a02 * a21);
    float adj02 =  (a01 * a12 - a02 * a11);
    float adj10 = -(a10 * a22 - a12 * a20);
    float adj11 =  (a00 * a22 - a02 * a20);
    float adj12 = -(a00 * a12 - a02 * a10);
    float adj20 =  (a10 * a21 - a11 * a20);
    float adj21 = -(a00 * a21 - a01 * a20);
    float adj22 =  (a00 * a11 - a01 * a10);

    float det = a00 * adj00 + a01 * adj10 + a02 * adj20;

    Binv[0][0] = __fdiv_rn(adj00, det); Binv[0][1] = __fdiv_rn(adj01, det); Binv[0][2] = __fdiv_rn(adj02, det);
    Binv[1][0] = __fdiv_rn(adj10, det); Binv[1][1] = __fdiv_rn(adj11, det); Binv[1][2] = __fdiv_rn(adj12, det);
    Binv[2][0] = __fdiv_rn(adj20, det); Binv[2][1] = __fdiv_rn(adj21, det); Binv[2][2] = __fdiv_rn(adj22, det);
}

// Replicates numpy rounding exactly (no FMA contraction):
// delta = pos_i - pos_j; frac = delta @ Binv; delta -= rint(frac) @ B; d2 = sum(delta^2)
__device__ __forceinline__ void min_image(float xi, float yi, float zi,
                                          float xj, float yj, float zj,
                                          const float B[3][3], const float Binv[3][3],
                                          float& dx, float& dy, float& dz, float& d2) {
    dx = __fsub_rn(xi, xj);
    dy = __fsub_rn(yi, yj);
    dz = __fsub_rn(zi, zj);

    float f0 = __fadd_rn(__fadd_rn(__fmul_rn(dx, Binv[0][0]), __fmul_rn(dy, Binv[1][0])), __fmul_rn(dz, Binv[2][0]));
    float f1 = __fadd_rn(__fadd_rn(__fmul_rn(dx, Binv[0][1]), __fmul_rn(dy, Binv[1][1])), __fmul_rn(dz, Binv[2][1]));
    float f2 = __fadd_rn(__fadd_rn(__fmul_rn(dx, Binv[0][2]), __fmul_rn(dy, Binv[1][2])), __fmul_rn(dz, Binv[2][2]));

    float r0 = rintf(f0), r1 = rintf(f1), r2 = rintf(f2);

    float c0 = __fadd_rn(__fadd_rn(__fmul_rn(r0, B[0][0]), __fmul_rn(r1, B[1][0])), __fmul_rn(r2, B[2][0]));
    float c1 = __fadd_rn(__fadd_rn(__fmul_rn(r0, B[0][1]), __fmul_rn(r1, B[1][1])), __fmul_rn(r2, B[2][1]));
    float c2 = __fadd_rn(__fadd_rn(__fmul_rn(r0, B[0][2]), __fmul_rn(r1, B[1][2])), __fmul_rn(r2, B[2][2]));

    dx = __fsub_rn(dx, c0);
    dy = __fsub_rn(dy, c1);
    dz = __fsub_rn(dz, c2);

    d2 = __fadd_rn(__fadd_rn(__fmul_rn(dx, dx), __fmul_rn(dy, dy)), __fmul_rn(dz, dz));
}

// Pad output (pairs=-1, rest=0) and repack positions [N,3] -> float4 [N].
__global__ void prep_kernel(const float* __restrict__ pos, float4* __restrict__ pos4,
                            float* __restrict__ out, int N, int P) {
    int idx = blockIdx.x * blockDim.x + threadIdx.x;
    int total = 6 * P + 1;
    for (int k = idx; k < total; k += gridDim.x * blockDim.x)
        out[k] = (k < 2 * P) ? -1.0f : 0.0f;
    if (idx < N)
        pos4[idx] = make_float4(pos[3 * idx], pos[3 * idx + 1], pos[3 * idx + 2], 0.0f);
}

// One wave per row i: count j>i hits and record per-chunk 64-bit hit masks.
__global__ void count_rows_kernel(const float4* __restrict__ pos4, const float* __restrict__ box,
                                  int* __restrict__ counts, unsigned long long* __restrict__ masks,
                                  int N) {
    int gwave = (blockIdx.x * blockDim.x + threadIdx.x) >> 6;
    int lane = threadIdx.x & 63;
    if (gwave >= N) return;
    int i = gwave;

    float B[3][3], Binv[3][3];
    load_box_inv(box, B, Binv);

    float4 pi = pos4[i];
    int nchunks = N >> 6;       // 64
    int c0 = i >> 6;            // first chunk containing j>i
    unsigned long long* mrow = masks + (size_t)i * nchunks;

    int cnt = 0;

    // First (diagonal) chunk: needs the j>i predicate.
    {
        int j = (c0 << 6) + lane;
        bool hit = false;
        if (j > i) {
            float4 pj = pos4[j];
            float dx, dy, dz, d2;
            min_image(pi.x, pi.y, pi.z, pj.x, pj.y, pj.z, B, Binv, dx, dy, dz, d2);
            hit = (d2 < CUT2);
        }
        unsigned long long m = __ballot(hit);
        if (lane == 0) mrow[c0] = m;
        cnt += __popcll(m);
    }

    // Remaining chunks: all j>i. Unroll x2 for ILP.
    int c = c0 + 1;
    for (; c + 2 <= nchunks; c += 2) {
        int j0 = (c << 6) + lane;
        float4 pj0 = pos4[j0];
        float4 pj1 = pos4[j0 + 64];
        float dx0, dy0, dz0, d20, dx1, dy1, dz1, d21;
        min_image(pi.x, pi.y, pi.z, pj0.x, pj0.y, pj0.z, B, Binv, dx0, dy0, dz0, d20);
        min_image(pi.x, pi.y, pi.z, pj1.x, pj1.y, pj1.z, B, Binv, dx1, dy1, dz1, d21);
        unsigned long long m0 = __ballot(d20 < CUT2);
        unsigned long long m1 = __ballot(d21 < CUT2);
        if (lane == 0) { mrow[c] = m0; mrow[c + 1] = m1; }
        cnt += __popcll(m0) + __popcll(m1);
    }
    if (c < nchunks) {
        int j = (c << 6) + lane;
        float4 pj = pos4[j];
        float dx, dy, dz, d2;
        min_image(pi.x, pi.y, pi.z, pj.x, pj.y, pj.z, B, Binv, dx, dy, dz, d2);
        unsigned long long m = __ballot(d2 < CUT2);
        if (lane == 0) mrow[c] = m;
        cnt += __popcll(m);
    }

    if (lane == 0) counts[i] = cnt;
}

// Single wave: exclusive scan of counts[N] -> offsets[N]; write n_pairs.
__global__ void scan_kernel(const int* __restrict__ counts, int* __restrict__ offsets,
                            float* __restrict__ out_npairs, int N) {
    int lane = threadIdx.x;          // 0..63
    int per = N >> 6;                // rows per lane
    int base_idx = lane * per;

    int sum = 0;
    for (int r = 0; r < per; ++r) sum += counts[base_idx + r];

    int incl = sum;
    #pragma unroll
    for (int d = 1; d < 64; d <<= 1) {
        int t = __shfl_up(incl, d);
        if (lane >= d) incl += t;
    }
    int run = incl - sum;            // exclusive base for this lane's span

    for (int r = 0; r < per; ++r) {
        int cv = counts[base_idx + r];
        offsets[base_idx + r] = run;
        run += cv;
    }
    if (lane == 63) *out_npairs = (float)incl;
}

// One wave per row i: ordered write of hits using precomputed masks.
// Only hit lanes recompute min_image; zero-mask chunks are skipped.
__global__ void fill_rows_kernel(const float4* __restrict__ pos4, const float* __restrict__ box,
                                 const int* __restrict__ offsets,
                                 const unsigned long long* __restrict__ masks,
                                 float* __restrict__ out, int N, int P) {
    int gwave = (blockIdx.x * blockDim.x + threadIdx.x) >> 6;
    int lane = threadIdx.x & 63;
    if (gwave >= N) return;
    int i = gwave;

    int nchunks = N >> 6;
    int c0 = i >> 6;

    // lane l holds the mask of chunk l for this row (chunks < c0 were never
    // written by count -> force to 0).
    unsigned long long mymask = masks[(size_t)i * nchunks + lane];
    if (lane < c0) mymask = 0ull;

    float B[3][3], Binv[3][3];
    load_box_inv(box, B, Binv);
    float4 pi = pos4[i];

    int base = offsets[i];
    for (int c = c0; c < nchunks; ++c) {
        unsigned long long m = __shfl(mymask, c);
        if (m != 0ull) {
            bool hit = (m >> lane) & 1ull;
            if (hit) {
                int j = (c << 6) + lane;
                float4 pj = pos4[j];
                float dx, dy, dz, d2;
                min_image(pi.x, pi.y, pi.z, pj.x, pj.y, pj.z, B, Binv, dx, dy, dz, d2);
                int slot = base + __popcll(m & ((1ull << lane) - 1ull));
                if (slot < P) {
                    out[slot] = (float)i;
                    out[P + slot] = (float)j;
                    size_t db = 2 * (size_t)P + 3 * (size_t)slot;
                    out[db + 0] = dx;
                    out[db + 1] = dy;
                    out[db + 2] = dz;
                    out[5 * (size_t)P + slot] = sqrtf(d2);
                }
            }
            base += __popcll(m);
        }
    }
}

extern "C" void kernel_launch(void* const* d_in, const int* in_sizes, int n_in,
                              void* d_out, int out_size, void* d_ws, size_t ws_size,
                              hipStream_t stream) {
    const float* pos = (const float*)d_in[0];
    const float* box = (const float*)d_in[1];
    float* out = (float*)d_out;

    int N = in_sizes[0] / 3;          // 4096
    int P = (out_size - 1) / 6;       // 131072
    int nchunks = N >> 6;

    // ws layout: counts[N] | offsets[N] | pos4[N] (16B) | masks[N*nchunks] (8B)
    char* w = (char*)d_ws;
    int* counts = (int*)w;                         w += (size_t)N * sizeof(int);
    int* offsets = (int*)w;                        w += (size_t)N * sizeof(int);
    float4* pos4 = (float4*)w;                     w += (size_t)N * sizeof(float4);
    unsigned long long* masks = (unsigned long long*)w;

    int total_out = 6 * P + 1;
    int pad_blocks = (total_out + 255) / 256;
    prep_kernel<<<pad_blocks, 256, 0, stream>>>(pos, pos4, out, N, P);

    int row_threads = N * 64;
    int row_blocks = (row_threads + 255) / 256;
    count_rows_kernel<<<row_blocks, 256, 0, stream>>>(pos4, box, counts, masks, N);

    scan_kernel<<<1, 64, 0, stream>>>(counts, offsets, out + 6 * (size_t)P, N);

    fill_rows_kernel<<<row_blocks, 256, 0, stream>>>(pos4, box, offsets, masks, out, N, P);
}